// Round 5
// baseline (338.531 us; speedup 1.0000x reference)
//
#include <hip/hip_runtime.h>
#include <hip/hip_bf16.h>
#include <math.h>

#define NB   16
#define CIN  128
#define COUT 128
#define HH   56
#define WW   56
#define LL   3136

typedef __attribute__((ext_vector_type(8))) short short8;
typedef __attribute__((ext_vector_type(16))) float f32x16;
typedef __attribute__((ext_vector_type(4))) float f32x4;
typedef __attribute__((ext_vector_type(4))) unsigned int uint4v;

// ---- mfma geometry ----
#define PXT    256            // pixels per block (linear)
#define NPXT   13             // ceil(3136/256)
#define XC     58             // cols incl halo
#define XPLANE 7424           // ushorts per x plane (8 rows * 58 * 16)
#define XUSH   14848          // ushorts per x buffer (hi+lo) = 29,696 B
#define XUNITS 1856           // 16B units per x buffer
#define XHALF  928            // units per plane
#define CPW    16             // weight row pitch (ushorts)
#define WS_TAP 1024           // ushorts per tap per plane (64 rows * 16)
#define WS_N   9216           // ushorts per plane (9 taps)
#define WUSH   18432          // ushorts per w buffer (hi+lo) = 36,864 B
#define WBYTES 36864          // bytes per (ocb,cg) weight image

// xt layout: [cg 8][bat 16][plane 2][row 62][col 58][16ch] ushorts (halo zeroed)
#define XT_ROWS 62
#define XT_PLANE_USH (XT_ROWS*XC*16)   // 57536
#define XT_CG_STRIDE 3682304           // bytes per cg slab

// ---- workspace layout (bytes) ----
#define CSD_OFF 256
#define WSP_OFF 32768
#define XT_OFF  1212416
#define XT_SIZE 29458432
#define WL_OFF  (XT_OFF + XT_SIZE)     // needs ws_size >= ~31MB

// ---------------- merged prep: weights (+csd, +cnt zero) and x layout ----------------
__global__ void prep_kernel(const float* __restrict__ w, const float* __restrict__ bk,
                            const float* __restrict__ x,
                            double* __restrict__ csd, unsigned short* __restrict__ wsp,
                            unsigned short* __restrict__ xt, unsigned* __restrict__ cnt) {
    int bid = blockIdx.x;
    if (bid == 0 && threadIdx.x == 0) *cnt = 0u;
    if (bid < 576) {
        // ---- weight part: fold cos/sin, bf16 hi/lo split, pre-swizzled LDS image ----
        int i = bid * 256 + threadIdx.x;
        if (i >= 9*COUT*CIN) return;
        int k = i / (COUT*CIN);
        int rem = i - k*(COUT*CIN);
        int oc = rem >> 7, c = rem & 127;
        double bkv = (double)bk[k*COUT + oc];
        double ck = cos(bkv), sk = sin(bkv);
        if (c == 0) {
            csd[k*COUT + oc]          = ck;
            csd[9*COUT + k*COUT + oc] = sk;
        }
        float wv = w[i];
        float fa = (float)(ck * (double)wv);
        float fb = (float)(sk * (double)wv);
        __hip_bfloat16 ah = __float2bfloat16(fa);
        __hip_bfloat16 al = __float2bfloat16(fa - __bfloat162float(ah));
        __hip_bfloat16 bh = __float2bfloat16(fb);
        __hip_bfloat16 bl = __float2bfloat16(fb - __bfloat162float(bh));
        int ocb = oc >> 5;
        int rowa = oc & 31, rowb = 32 + rowa;
        int cg = c >> 4, cp = c & 15;
        int sl = (((cp >> 3) ^ ((rowa >> 2) & 1)) << 3) | (cp & 7);
        size_t img = ((size_t)ocb*8 + cg) * (WBYTES/2);
        wsp[img + (size_t)k*WS_TAP + rowa*CPW + sl]        = *(unsigned short*)&ah;
        wsp[img + (size_t)k*WS_TAP + rowb*CPW + sl]        = *(unsigned short*)&bh;
        wsp[img + WS_N + (size_t)k*WS_TAP + rowa*CPW + sl] = *(unsigned short*)&al;
        wsp[img + WS_N + (size_t)k*WS_TAP + rowb*CPW + sl] = *(unsigned short*)&bl;
    } else {
        // ---- x part: bf16 hi/lo transposed padded layout ----
        int i = (bid - 576) * 256 + threadIdx.x;     // 852*256 = 218112
        if (i < 100352) {
            int c4 = i % 14; int t = i / 14;
            int row1 = t % 56; t /= 56;
            int bat = t & 15, cg = t >> 4;
            const float* xp = x + ((size_t)(bat*CIN + cg*16))*LL + row1*WW + c4*4;
            unsigned short hi[4][16], lo[4][16];
            #pragma unroll
            for (int j = 0; j < 16; j++) {
                f32x4 v = *(const f32x4*)(xp + (size_t)j*LL);
                #pragma unroll
                for (int cc = 0; cc < 4; cc++) {
                    float f = v[cc];
                    __hip_bfloat16 h = __float2bfloat16(f);
                    __hip_bfloat16 l = __float2bfloat16(f - __bfloat162float(h));
                    hi[cc][j] = *(unsigned short*)&h;
                    lo[cc][j] = *(unsigned short*)&l;
                }
            }
            size_t base = ((((size_t)cg*16 + bat)*2 + 0)*XT_ROWS + (row1+1))*XC + (c4*4 + 1);
            #pragma unroll
            for (int cc = 0; cc < 4; cc++) {
                unsigned short* dh = xt + (base + cc)*16;
                unsigned short* dl = dh + XT_PLANE_USH;
                *(uint4v*)dh       = *(const uint4v*)&hi[cc][0];
                *(uint4v*)(dh + 8) = *(const uint4v*)&hi[cc][8];
                *(uint4v*)dl       = *(const uint4v*)&lo[cc][0];
                *(uint4v*)(dl + 8) = *(const uint4v*)&lo[cc][8];
            }
        } else if (i < 218112) {
            int i2 = i - 100352;                      // < 117760
            int unit = i2 % 460; int t = i2 / 460;
            int pl = t & 1; t >>= 1;
            int bat = t & 15, cg = t >> 4;
            int row, c58;
            if (unit < 348) {
                int zr = unit / 58; c58 = unit - zr*58;
                row = (zr == 0) ? 0 : (56 + zr);
            } else {
                int u2 = unit - 348; row = 1 + (u2 >> 1); c58 = (u2 & 1) ? 57 : 0;
            }
            size_t base = ((((size_t)cg*16 + bat)*2 + pl)*XT_ROWS + row)*XC + c58;
            uint4v zz = {0u,0u,0u,0u};
            *(uint4v*)(xt + base*16)     = zz;
            *(uint4v*)(xt + base*16 + 8) = zz;
        }
    }
}

// ---------------- main MFMA kernel: 8 waves, FULL x+w double-buffer, 1 barrier/chunk ----------------
__global__ __launch_bounds__(512, 1)
void mfma_kernel(const unsigned short* __restrict__ xt, const unsigned short* __restrict__ wsp,
                 const float* __restrict__ bias, float* __restrict__ out,
                 unsigned* __restrict__ cnt, unsigned* __restrict__ wl, unsigned cap)
{
    __shared__ __align__(16) unsigned short SMX[2*XUSH];   // 59,392 B
    __shared__ __align__(16) unsigned short SMW[2*WUSH];   // 73,728 B  (total 133,120 B -> 1 blk/CU)
    __shared__ float sm_bias[32];

    const int tid = threadIdx.x;
    // XCD-chunked bijective swizzle (832 % 8 == 0)
    int bid = blockIdx.x;
    int wk = (bid & 7) * 104 + (bid >> 3);
    const int ocb = wk & 3; wk >>= 2;
    const int pxt = wk % NPXT;
    const int bat = wk / NPXT;
    const int l0  = pxt * PXT;
    const int o0  = ocb * 32;
    const int yf  = l0 / WW;

    const int lane = tid & 63;
    const int n    = lane & 31;
    const int kh   = lane >> 5;
    const int wave = tid >> 6;

    if (tid < 32) sm_bias[tid] = bias[o0 + tid];

    // per-lane global source offsets for x staging (bytes within one cg-slab)
    unsigned xoff[4];
    #pragma unroll
    for (int k = 0; k < 4; k++) {
        int u = tid + 512*k;
        int uc = u < XUNITS ? u : XUNITS-1;
        int pl = uc >= XHALF ? 1 : 0;
        int rem = uc - pl*XHALF;
        int q  = rem >> 1;
        int hl = rem & 1;
        int hg = hl ^ ((q >> 2) & 1);        // inverse of read-side bank swizzle
        int r  = q / XC;
        int c  = q - r*XC;
        xoff[k] = (unsigned)((((bat*2 + pl)*XT_ROWS + (yf + r))*XC + c)*32 + hg*16);
    }

    // this wave's B-frag pixel slot (1 group of 32 pixels per wave)
    int p  = l0 + wave*32 + n;
    int pc = p < LL ? p : LL-1;
    int py = pc / WW, pxx = pc - py*WW;
    const int q0 = (py - yf)*XC + pxx;

    const int sw  = ((((n>>2)&1) ^ kh) << 3);
    const int iAa = n*CPW + sw;
    const int iAb = (32+n)*CPW + sw;

    f32x16 acc_a, acc_b;
    #pragma unroll
    for (int r = 0; r < 16; r++) { acc_a[r] = 0.f; acc_b[r] = 0.f; }

    const char* xtB  = (const char*)xt;
    const char* wspB = (const char*)wsp + (size_t)ocb * (8*(size_t)WBYTES);

    // async x stage into ping-pong slot (chn&1): linear LDS dest, swizzle folded into source
    auto stage_x = [&](int chn) {
        const char* xp = xtB + (size_t)chn * XT_CG_STRIDE;
        unsigned short* dst = &SMX[(chn & 1) * XUSH];
        #pragma unroll
        for (int k = 0; k < 3; k++) {
            __builtin_amdgcn_global_load_lds(
                (const __attribute__((address_space(1))) unsigned int*)(xp + xoff[k]),
                (__attribute__((address_space(3))) unsigned int*)&dst[(wave*64 + 512*k)*8],
                16, 0, 0);
        }
        if (wave < 5)                              // 1856 = 3*512 + 5*64
            __builtin_amdgcn_global_load_lds(
                (const __attribute__((address_space(1))) unsigned int*)(xp + xoff[3]),
                (__attribute__((address_space(3))) unsigned int*)&dst[(1536 + wave*64)*8],
                16, 0, 0);
    };
    // async w stage: wsp image is byte-identical to the LDS image -> pure linear copy
    auto stage_w = [&](int chn) {
        const char* wp = wspB + (size_t)chn * (size_t)WBYTES;
        unsigned short* dst = &SMW[(chn & 1) * WUSH];
        #pragma unroll
        for (int k = 0; k < 4; k++) {
            __builtin_amdgcn_global_load_lds(
                (const __attribute__((address_space(1))) unsigned int*)(wp + (tid + 512*k)*16),
                (__attribute__((address_space(3))) unsigned int*)&dst[(wave*64 + 512*k)*8],
                16, 0, 0);
        }
        if (wave < 4)                              // 2304 = 4*512 + 4*64
            __builtin_amdgcn_global_load_lds(
                (const __attribute__((address_space(1))) unsigned int*)(wp + (2048 + tid)*16),
                (__attribute__((address_space(3))) unsigned int*)&dst[(2048 + wave*64)*8],
                16, 0, 0);
    };

    // prologue: stage chunk 0 into slot 0, single exposed drain
    stage_x(0);
    stage_w(0);
    __syncthreads();

    #pragma unroll 1
    for (int ch = 0; ch < 8; ch++) {
        // issue next chunk's stage FIRST (into the slot freed at the previous barrier);
        // its latency rides under this chunk's entire compute phase
        if (ch < 7) { stage_x(ch+1); stage_w(ch+1); }
        const unsigned short* smx = &SMX[(ch & 1) * XUSH];
        const unsigned short* smw = &SMW[(ch & 1) * WUSH];
        // tap loop: ZERO VMEM — pure ds_read + MFMA (compiler-managed lgkmcnt)
        #pragma unroll
        for (int tap = 0; tap < 9; tap++) {
            const int ky = tap / 3, kx = tap - 3*ky;
            short8 Aha = *(const short8*)&smw[tap*WS_TAP + iAa];
            short8 Ahb = *(const short8*)&smw[tap*WS_TAP + iAb];
            short8 Ala = *(const short8*)&smw[WS_N + tap*WS_TAP + iAa];
            short8 Alb = *(const short8*)&smw[WS_N + tap*WS_TAP + iAb];
            int q  = q0 + ky*XC + kx;
            int si = q*16 + ((kh ^ ((q>>2)&1)) << 3);
            short8 Bh = *(const short8*)&smx[si];
            short8 Bl = *(const short8*)&smx[XPLANE + si];
            __builtin_amdgcn_s_setprio(1);
            acc_a = __builtin_amdgcn_mfma_f32_32x32x16_bf16(Ala, Bh, acc_a, 0,0,0);
            acc_a = __builtin_amdgcn_mfma_f32_32x32x16_bf16(Aha, Bl, acc_a, 0,0,0);
            acc_a = __builtin_amdgcn_mfma_f32_32x32x16_bf16(Aha, Bh, acc_a, 0,0,0);
            acc_b = __builtin_amdgcn_mfma_f32_32x32x16_bf16(Alb, Bh, acc_b, 0,0,0);
            acc_b = __builtin_amdgcn_mfma_f32_32x32x16_bf16(Ahb, Bl, acc_b, 0,0,0);
            acc_b = __builtin_amdgcn_mfma_f32_32x32x16_bf16(Ahb, Bh, acc_b, 0,0,0);
            __builtin_amdgcn_s_setprio(0);
        }
        // single barrier per chunk: implicit vmcnt(0) is cheap (loads landed during compute)
        if (ch < 7) __syncthreads();
    }

    // ---- epilogue: algebraic magnitude (no sinf/cosf), atanf only for theta ----
    const float eps = 1e-05f;
    const float PIf = 3.14159265358979323846f;
    size_t obase = (size_t)bat * (2*COUT) * LL;
    const int pcol = wave*32 + n;
    const int pp = l0 + pcol;

    #pragma unroll
    for (int r = 0; r < 16; r++) {
        int row = (r & 3) + 8*(r >> 2) + 4*kh;
        float av = acc_a[r];
        float bv = acc_b[r];
        bool flag = (pp < LL) &&
                    (fabsf(av) < 1.5e-4f || (bv < 1.05e-5f && bv > -2.05e-5f));
        unsigned long long m = __ballot(flag);
        if (m) {
            int leader = (int)__ffsll((long long)m) - 1;
            unsigned base = 0;
            if (lane == leader) base = atomicAdd(cnt, (unsigned)__popcll(m));
            base = __shfl(base, leader);
            if (flag) {
                unsigned slot = base + (unsigned)__popcll(m & ((1ULL << lane) - 1ULL));
                if (slot < cap)
                    wl[slot] = ((unsigned)(bat*LL + pp) << 7) | (unsigned)(o0 + row);
            }
        }
        bool ag = av > 0.f, bg = bv > 0.f;
        bool eq = (ag == bg);
        float ratio = eq ? (bv / (av + eps)) : (av / (bv + eps));
        float at = atanf(ratio);
        float peak = eq ? (ag ? PIf*0.5f : -PIf*0.5f) : (bg ? 0.0f : -PIf);
        float th = peak - (eq ? at : -at);
        // o = sin(th)*a + cos(th)*b == sgn * rsqrt(1+r^2) * (eq ? a + r*b : r*a + b)
        float c = 1.0f / sqrtf(1.0f + ratio*ratio);
        float t = eq ? (av + ratio*bv) : (ratio*av + bv);
        bool pos = eq ? ag : bg;
        float o = (pos ? c : -c) * t;
        if (pp < LL) {
            out[obase + (size_t)(o0+row)*LL + pp]      = o + sm_bias[row];
            out[obase + (size_t)(COUT+o0+row)*LL + pp] = th * (1.0f/PIf);
        }
    }
}

// ---------------- fp64 fixup for near-discontinuity elements ----------------
__global__ __launch_bounds__(256)
void fixup_kernel(const float* __restrict__ x, const float* __restrict__ w,
                  const double* __restrict__ csd, const float* __restrict__ bias,
                  const unsigned* __restrict__ cnt, const unsigned* __restrict__ wl,
                  unsigned cap, float* __restrict__ out) {
    const int lane   = threadIdx.x & 63;
    const int waveid = (blockIdx.x * 256 + threadIdx.x) >> 6;
    const int nwaves = gridDim.x * 4;
    unsigned nf = *cnt; if (nf > cap) nf = cap;
    const double PI = 3.14159265358979323846;

    for (unsigned u = waveid; u < nf; u += nwaves) {
        unsigned idx = wl[u];
        int oc = idx & 127;
        unsigned rest = idx >> 7;
        int bb_ = rest / LL;
        int l   = rest - bb_*LL;
        int yy  = l / WW;
        int xx  = l - yy*WW;
        const float* xb = x + (size_t)bb_ * CIN * LL;

        double pa = 0.0, pb = 0.0;
        #pragma unroll
        for (int k = 0; k < 9; k++) {
            int dy = k/3, dx = k - dy*3;
            int py = yy + dy - 1, px = xx + dx - 1;
            double pk = 0.0;
            if ((unsigned)py < HH && (unsigned)px < WW) {
                int base = py*WW + px;
                const float* wr = w + k*(COUT*CIN) + oc*CIN;
                int c = lane;
                pk  = (double)xb[(size_t)c*LL + base] * (double)wr[c];
                c = lane + 64;
                pk += (double)xb[(size_t)c*LL + base] * (double)wr[c];
            }
            pa += csd[k*COUT + oc] * pk;
            pb += csd[9*COUT + k*COUT + oc] * pk;
        }
        #pragma unroll
        for (int off = 32; off > 0; off >>= 1) {
            pa += __shfl_xor(pa, off, 64);
            pb += __shfl_xor(pb, off, 64);
        }
        if (lane == 0) {
            bool ag = pa > 0.0, bg = pb > 0.0;
            bool eq = (ag == bg);
            double th;
            if (eq) th = (ag ? PI*0.5 : -PI*0.5) - atan(pb / (pa + 1e-5));
            else    th = (bg ? 0.0 : -PI) + atan(pa / (pb + 1e-5));
            double o = sin(th)*pa + cos(th)*pb + (double)bias[oc];
            out[((size_t)bb_*(2*COUT) + oc) * LL + l]        = (float)o;
            out[((size_t)bb_*(2*COUT) + COUT + oc) * LL + l] = (float)(th / PI);
        }
    }
}

extern "C" void kernel_launch(void* const* d_in, const int* in_sizes, int n_in,
                              void* d_out, int out_size, void* d_ws, size_t ws_size,
                              hipStream_t stream) {
    const float* x    = (const float*)d_in[0];
    const float* w    = (const float*)d_in[1];
    const float* bk   = (const float*)d_in[2];
    const float* bias = (const float*)d_in[3];
    float* out = (float*)d_out;

    char* ws = (char*)d_ws;
    unsigned*       cnt = (unsigned*)ws;
    double*         csd = (double*)(ws + CSD_OFF);
    unsigned short* wsp = (unsigned short*)(ws + WSP_OFF);
    unsigned short* xt  = (unsigned short*)(ws + XT_OFF);
    unsigned*       wl  = (unsigned*)(ws + WL_OFF);
    unsigned cap = (ws_size > (size_t)WL_OFF + 4096) ? (unsigned)((ws_size - WL_OFF) / 4) : 0u;

    hipLaunchKernelGGL(prep_kernel,  dim3(1428), dim3(256), 0, stream,
                       w, bk, x, csd, wsp, xt, cnt);
    hipLaunchKernelGGL(mfma_kernel,  dim3(NB*NPXT*4), dim3(512), 0, stream,
                       xt, wsp, bias, out, cnt, wl, cap);
    hipLaunchKernelGGL(fixup_kernel, dim3(256), dim3(256), 0, stream,
                       x, w, csd, bias, cnt, wl, cap, out);
}

// Round 6
// 338.420 us; speedup vs baseline: 1.0003x; 1.0003x over previous
//
#include <hip/hip_runtime.h>
#include <hip/hip_bf16.h>
#include <math.h>

#define NB   16
#define CIN  128
#define COUT 128
#define HH   56
#define WW   56
#define LL   3136

typedef __attribute__((ext_vector_type(8))) short short8;
typedef __attribute__((ext_vector_type(16))) float f32x16;
typedef __attribute__((ext_vector_type(4))) float f32x4;
typedef __attribute__((ext_vector_type(4))) unsigned int uint4v;

// ---- mfma geometry ----
#define PXT    256            // pixels per block (linear)
#define NPXT   13             // ceil(3136/256)
#define XC     58             // cols incl halo
#define XPLANE 7424           // ushorts per x plane (8 rows * 58 * 16)
#define XUSH   14848          // ushorts x buffer (hi+lo) = 29,696 B
#define XUNITS 1856           // 16B units in x buffer
#define XHALF  928            // units per plane
#define WUSH   18432          // ushorts w buffer = 36,864 B
#define WBYTES 36864          // bytes per (ocb,cg) weight image
#define WUNITS 2304           // 16B units in w buffer

// frag-major weight image: [tap 9][frag 4][lane 64][8 ush]; frag: 0=Aha 1=Ahb 2=Ala 3=Alb

// xt layout: [cg 8][bat 16][plane 2][row 62][col 58][16ch] ushorts (halo zeroed)
#define XT_ROWS 62
#define XT_PLANE_USH (XT_ROWS*XC*16)   // 57536
#define XT_CG_STRIDE 3682304           // bytes per cg slab

// ---- workspace layout (bytes) ----
#define CSD_OFF 256
#define WSP_OFF 32768
#define XT_OFF  1212416
#define XT_SIZE 29458432
#define WL_OFF  (XT_OFF + XT_SIZE)     // needs ws_size >= ~31MB

// ---------------- merged prep: weights (+csd, +cnt zero) and x layout ----------------
__global__ void prep_kernel(const float* __restrict__ w, const float* __restrict__ bk,
                            const float* __restrict__ x,
                            double* __restrict__ csd, unsigned short* __restrict__ wsp,
                            unsigned short* __restrict__ xt, unsigned* __restrict__ cnt) {
    int bid = blockIdx.x;
    if (bid == 0 && threadIdx.x == 0) *cnt = 0u;
    if (bid < 576) {
        // ---- weight part: fold cos/sin (fp32), bf16 hi/lo split, FRAG-MAJOR image ----
        int i = bid * 256 + threadIdx.x;
        if (i >= 9*COUT*CIN) return;
        int k = i / (COUT*CIN);
        int rem = i - k*(COUT*CIN);
        int oc = rem >> 7, c = rem & 127;
        float bkv = bk[k*COUT + oc];
        if (c == 0) {                      // fp64 trig only for the fixup table
            double bd = (double)bkv;
            csd[k*COUT + oc]          = cos(bd);
            csd[9*COUT + k*COUT + oc] = sin(bd);
        }
        float ck = cosf(bkv), sk = sinf(bkv);
        float wv = w[i];
        float fa = ck * wv;
        float fb = sk * wv;
        __hip_bfloat16 ah = __float2bfloat16(fa);
        __hip_bfloat16 al = __float2bfloat16(fa - __bfloat162float(ah));
        __hip_bfloat16 bh = __float2bfloat16(fb);
        __hip_bfloat16 bl = __float2bfloat16(fb - __bfloat162float(bh));
        int ocb = oc >> 5;
        int rowa = oc & 31;
        int cg = c >> 4, cp = c & 15;
        int lane = rowa + ((cp >> 3) << 5);   // lane = row + 32*(hi-half of 16ch)
        int bp = cp & 7;
        size_t img = ((size_t)ocb*8 + cg) * WUSH;
        wsp[img + (size_t)((k*4+0)*64 + lane)*8 + bp] = *(unsigned short*)&ah;
        wsp[img + (size_t)((k*4+1)*64 + lane)*8 + bp] = *(unsigned short*)&bh;
        wsp[img + (size_t)((k*4+2)*64 + lane)*8 + bp] = *(unsigned short*)&al;
        wsp[img + (size_t)((k*4+3)*64 + lane)*8 + bp] = *(unsigned short*)&bl;
    } else {
        // ---- x part: bf16 hi/lo transposed padded layout ----
        int i = (bid - 576) * 256 + threadIdx.x;     // 852*256 = 218112
        if (i < 100352) {
            int c4 = i % 14; int t = i / 14;
            int row1 = t % 56; t /= 56;
            int bat = t & 15, cg = t >> 4;
            const float* xp = x + ((size_t)(bat*CIN + cg*16))*LL + row1*WW + c4*4;
            unsigned short hi[4][16], lo[4][16];
            #pragma unroll
            for (int j = 0; j < 16; j++) {
                f32x4 v = *(const f32x4*)(xp + (size_t)j*LL);
                #pragma unroll
                for (int cc = 0; cc < 4; cc++) {
                    float f = v[cc];
                    __hip_bfloat16 h = __float2bfloat16(f);
                    __hip_bfloat16 l = __float2bfloat16(f - __bfloat162float(h));
                    hi[cc][j] = *(unsigned short*)&h;
                    lo[cc][j] = *(unsigned short*)&l;
                }
            }
            size_t base = ((((size_t)cg*16 + bat)*2 + 0)*XT_ROWS + (row1+1))*XC + (c4*4 + 1);
            #pragma unroll
            for (int cc = 0; cc < 4; cc++) {
                unsigned short* dh = xt + (base + cc)*16;
                unsigned short* dl = dh + XT_PLANE_USH;
                *(uint4v*)dh       = *(const uint4v*)&hi[cc][0];
                *(uint4v*)(dh + 8) = *(const uint4v*)&hi[cc][8];
                *(uint4v*)dl       = *(const uint4v*)&lo[cc][0];
                *(uint4v*)(dl + 8) = *(const uint4v*)&lo[cc][8];
            }
        } else if (i < 218112) {
            int i2 = i - 100352;                      // < 117760
            int unit = i2 % 460; int t = i2 / 460;
            int pl = t & 1; t >>= 1;
            int bat = t & 15, cg = t >> 4;
            int row, c58;
            if (unit < 348) {
                int zr = unit / 58; c58 = unit - zr*58;
                row = (zr == 0) ? 0 : (56 + zr);
            } else {
                int u2 = unit - 348; row = 1 + (u2 >> 1); c58 = (u2 & 1) ? 57 : 0;
            }
            size_t base = ((((size_t)cg*16 + bat)*2 + pl)*XT_ROWS + row)*XC + c58;
            uint4v zz = {0u,0u,0u,0u};
            *(uint4v*)(xt + base*16)     = zz;
            *(uint4v*)(xt + base*16 + 8) = zz;
        }
    }
}

// ---------------- main MFMA kernel: 4 waves x G=2, frag-major A, 2-phase, 2 blk/CU ----------------
__global__ __launch_bounds__(256, 2)
void mfma_kernel(const unsigned short* __restrict__ xt, const unsigned short* __restrict__ wsp,
                 const float* __restrict__ bias, float* __restrict__ out,
                 unsigned* __restrict__ cnt, unsigned* __restrict__ wl, unsigned cap)
{
    __shared__ __align__(16) unsigned short SMX[XUSH];   // 29,696 B
    __shared__ __align__(16) unsigned short SMW[WUSH];   // 36,864 B  (total 66,560 -> 2 blk/CU)
    __shared__ float sm_bias[32];

    const int tid = threadIdx.x;
    // XCD-chunked bijective swizzle (832 % 8 == 0)
    int bid = blockIdx.x;
    int wk = (bid & 7) * 104 + (bid >> 3);
    const int ocb = wk & 3; wk >>= 2;
    const int pxt = wk % NPXT;
    const int bat = wk / NPXT;
    const int l0  = pxt * PXT;
    const int o0  = ocb * 32;
    const int yf  = l0 / WW;

    const int lane = tid & 63;
    const int n    = lane & 31;
    const int kh   = lane >> 5;
    const int wave = tid >> 6;

    if (tid < 32) sm_bias[tid] = bias[o0 + tid];

    // per-lane global source offsets for x staging (bytes within one cg-slab)
    unsigned xoff[8];
    #pragma unroll
    for (int k = 0; k < 8; k++) {
        int u = tid + 256*k;
        int uc = u < XUNITS ? u : XUNITS-1;
        int pl = uc >= XHALF ? 1 : 0;
        int rem = uc - pl*XHALF;
        int q  = rem >> 1;
        int hl = rem & 1;
        int hg = hl ^ ((q >> 2) & 1);        // inverse of read-side bank swizzle
        int r  = q / XC;
        int c  = q - r*XC;
        xoff[k] = (unsigned)((((bat*2 + pl)*XT_ROWS + (yf + r))*XC + c)*32 + hg*16);
    }

    // B-frag pixel slots (2 groups of 32 px per wave)
    int q0g[2];
    #pragma unroll
    for (int g = 0; g < 2; g++) {
        int p  = l0 + wave*64 + g*32 + n;
        int pc = p < LL ? p : LL-1;
        int py = pc / WW, pxx = pc - py*WW;
        q0g[g] = (py - yf)*XC + pxx;
    }

    f32x16 acc_a[2], acc_b[2];
    #pragma unroll
    for (int g = 0; g < 2; g++) {
        #pragma unroll
        for (int r = 0; r < 16; r++) { acc_a[g][r] = 0.f; acc_b[g][r] = 0.f; }
    }

    const char* xtB  = (const char*)xt;
    const char* wspB = (const char*)wsp + (size_t)ocb * (8*(size_t)WBYTES);

    // async x stage: linear LDS dest, swizzle folded into per-lane source
    auto stage_x = [&](int chn) {
        const char* xp = xtB + (size_t)chn * XT_CG_STRIDE;
        #pragma unroll
        for (int k = 0; k < 7; k++) {
            __builtin_amdgcn_global_load_lds(
                (const __attribute__((address_space(1))) unsigned int*)(xp + xoff[k]),
                (__attribute__((address_space(3))) unsigned int*)&SMX[(wave*64 + 256*k)*8],
                16, 0, 0);
        }
        if (wave == 0)                             // 1856 = 7*256 + 64
            __builtin_amdgcn_global_load_lds(
                (const __attribute__((address_space(1))) unsigned int*)(xp + xoff[7]),
                (__attribute__((address_space(3))) unsigned int*)&SMX[1792*8],
                16, 0, 0);
    };
    // async w stage: frag-major image is a pure linear copy (2304 = 9*256 units)
    auto stage_w = [&](int chn) {
        const char* wp = wspB + (size_t)chn * (size_t)WBYTES;
        #pragma unroll
        for (int k = 0; k < 9; k++) {
            __builtin_amdgcn_global_load_lds(
                (const __attribute__((address_space(1))) unsigned int*)(wp + (tid + 256*k)*16),
                (__attribute__((address_space(3))) unsigned int*)&SMW[(wave*64 + 256*k)*8],
                16, 0, 0);
        }
    };

    // prologue: stage chunk 0, single drain
    stage_x(0);
    stage_w(0);
    __syncthreads();

    const unsigned short* awp = &SMW[lane*8];     // frag reads: awp + const offsets (conflict-free)

    #pragma unroll 1
    for (int ch = 0; ch < 8; ch++) {
        // tap loop: ZERO VMEM — pure ds_read + MFMA
        #pragma unroll
        for (int tap = 0; tap < 9; tap++) {
            const int ky = tap / 3, kx = tap - 3*ky;
            short8 Aha = *(const short8*)&awp[(tap*4+0)*512];
            short8 Ahb = *(const short8*)&awp[(tap*4+1)*512];
            short8 Ala = *(const short8*)&awp[(tap*4+2)*512];
            short8 Alb = *(const short8*)&awp[(tap*4+3)*512];
            __builtin_amdgcn_s_setprio(1);
            #pragma unroll
            for (int g = 0; g < 2; g++) {
                int q  = q0g[g] + ky*XC + kx;
                int si = q*16 + ((kh ^ ((q>>2)&1)) << 3);
                short8 Bh = *(const short8*)&SMX[si];
                short8 Bl = *(const short8*)&SMX[XPLANE + si];
                acc_a[g] = __builtin_amdgcn_mfma_f32_32x32x16_bf16(Ala, Bh, acc_a[g], 0,0,0);
                acc_a[g] = __builtin_amdgcn_mfma_f32_32x32x16_bf16(Aha, Bl, acc_a[g], 0,0,0);
                acc_a[g] = __builtin_amdgcn_mfma_f32_32x32x16_bf16(Aha, Bh, acc_a[g], 0,0,0);
                acc_b[g] = __builtin_amdgcn_mfma_f32_32x32x16_bf16(Alb, Bh, acc_b[g], 0,0,0);
                acc_b[g] = __builtin_amdgcn_mfma_f32_32x32x16_bf16(Ahb, Bl, acc_b[g], 0,0,0);
                acc_b[g] = __builtin_amdgcn_mfma_f32_32x32x16_bf16(Ahb, Bh, acc_b[g], 0,0,0);
            }
            __builtin_amdgcn_s_setprio(0);
        }
        if (ch < 7) {
            __syncthreads();                // readers done with LDS
            stage_x(ch+1);                  // async refill
            stage_w(ch+1);
            __syncthreads();                // drain; sibling block covers this
        }
    }

    // ---- epilogue: algebraic magnitude (no sinf/cosf), atanf only for theta ----
    const float eps = 1e-05f;
    const float PIf = 3.14159265358979323846f;
    size_t obase = (size_t)bat * (2*COUT) * LL;

    #pragma unroll
    for (int g = 0; g < 2; g++) {
        const int pcol = wave*64 + g*32 + n;
        const int pp = l0 + pcol;
        #pragma unroll
        for (int r = 0; r < 16; r++) {
            int row = (r & 3) + 8*(r >> 2) + 4*kh;
            float av = acc_a[g][r];
            float bv = acc_b[g][r];
            bool flag = (pp < LL) &&
                        (fabsf(av) < 1.5e-4f || (bv < 1.05e-5f && bv > -2.05e-5f));
            unsigned long long m = __ballot(flag);
            if (m) {
                int leader = (int)__ffsll((long long)m) - 1;
                unsigned base = 0;
                if (lane == leader) base = atomicAdd(cnt, (unsigned)__popcll(m));
                base = __shfl(base, leader);
                if (flag) {
                    unsigned slot = base + (unsigned)__popcll(m & ((1ULL << lane) - 1ULL));
                    if (slot < cap)
                        wl[slot] = ((unsigned)(bat*LL + pp) << 7) | (unsigned)(o0 + row);
                }
            }
            bool ag = av > 0.f, bg = bv > 0.f;
            bool eq = (ag == bg);
            float ratio = eq ? (bv / (av + eps)) : (av / (bv + eps));
            float at = atanf(ratio);
            float peak = eq ? (ag ? PIf*0.5f : -PIf*0.5f) : (bg ? 0.0f : -PIf);
            float th = peak - (eq ? at : -at);
            // o = sin(th)*a + cos(th)*b == sgn * rsqrt(1+r^2) * (eq ? a + r*b : r*a + b)
            float c = 1.0f / sqrtf(1.0f + ratio*ratio);
            float t = eq ? (av + ratio*bv) : (ratio*av + bv);
            bool pos = eq ? ag : bg;
            float o = (pos ? c : -c) * t;
            if (pp < LL) {
                out[obase + (size_t)(o0+row)*LL + pp]      = o + sm_bias[row];
                out[obase + (size_t)(COUT+o0+row)*LL + pp] = th * (1.0f/PIf);
            }
        }
    }
}

// ---------------- fp64 fixup for near-discontinuity elements ----------------
__global__ __launch_bounds__(256)
void fixup_kernel(const float* __restrict__ x, const float* __restrict__ w,
                  const double* __restrict__ csd, const float* __restrict__ bias,
                  const unsigned* __restrict__ cnt, const unsigned* __restrict__ wl,
                  unsigned cap, float* __restrict__ out) {
    const int lane   = threadIdx.x & 63;
    const int waveid = (blockIdx.x * 256 + threadIdx.x) >> 6;
    const int nwaves = gridDim.x * 4;
    unsigned nf = *cnt; if (nf > cap) nf = cap;
    const double PI = 3.14159265358979323846;

    for (unsigned u = waveid; u < nf; u += nwaves) {
        unsigned idx = wl[u];
        int oc = idx & 127;
        unsigned rest = idx >> 7;
        int bb_ = rest / LL;
        int l   = rest - bb_*LL;
        int yy  = l / WW;
        int xx  = l - yy*WW;
        const float* xb = x + (size_t)bb_ * CIN * LL;

        double pa = 0.0, pb = 0.0;
        #pragma unroll
        for (int k = 0; k < 9; k++) {
            int dy = k/3, dx = k - dy*3;
            int py = yy + dy - 1, px = xx + dx - 1;
            double pk = 0.0;
            if ((unsigned)py < HH && (unsigned)px < WW) {
                int base = py*WW + px;
                const float* wr = w + k*(COUT*CIN) + oc*CIN;
                int c = lane;
                pk  = (double)xb[(size_t)c*LL + base] * (double)wr[c];
                c = lane + 64;
                pk += (double)xb[(size_t)c*LL + base] * (double)wr[c];
            }
            pa += csd[k*COUT + oc] * pk;
            pb += csd[9*COUT + k*COUT + oc] * pk;
        }
        #pragma unroll
        for (int off = 32; off > 0; off >>= 1) {
            pa += __shfl_xor(pa, off, 64);
            pb += __shfl_xor(pb, off, 64);
        }
        if (lane == 0) {
            bool ag = pa > 0.0, bg = pb > 0.0;
            bool eq = (ag == bg);
            double th;
            if (eq) th = (ag ? PI*0.5 : -PI*0.5) - atan(pb / (pa + 1e-5));
            else    th = (bg ? 0.0 : -PI) + atan(pa / (pb + 1e-5));
            double o = sin(th)*pa + cos(th)*pb + (double)bias[oc];
            out[((size_t)bb_*(2*COUT) + oc) * LL + l]        = (float)o;
            out[((size_t)bb_*(2*COUT) + COUT + oc) * LL + l] = (float)(th / PI);
        }
    }
}

extern "C" void kernel_launch(void* const* d_in, const int* in_sizes, int n_in,
                              void* d_out, int out_size, void* d_ws, size_t ws_size,
                              hipStream_t stream) {
    const float* x    = (const float*)d_in[0];
    const float* w    = (const float*)d_in[1];
    const float* bk   = (const float*)d_in[2];
    const float* bias = (const float*)d_in[3];
    float* out = (float*)d_out;

    char* ws = (char*)d_ws;
    unsigned*       cnt = (unsigned*)ws;
    double*         csd = (double*)(ws + CSD_OFF);
    unsigned short* wsp = (unsigned short*)(ws + WSP_OFF);
    unsigned short* xt  = (unsigned short*)(ws + XT_OFF);
    unsigned*       wl  = (unsigned*)(ws + WL_OFF);
    unsigned cap = (ws_size > (size_t)WL_OFF + 4096) ? (unsigned)((ws_size - WL_OFF) / 4) : 0u;

    hipLaunchKernelGGL(prep_kernel,  dim3(1428), dim3(256), 0, stream,
                       w, bk, x, csd, wsp, xt, cnt);
    hipLaunchKernelGGL(mfma_kernel,  dim3(NB*NPXT*4), dim3(256), 0, stream,
                       xt, wsp, bias, out, cnt, wl, cap);
    hipLaunchKernelGGL(fixup_kernel, dim3(256), dim3(256), 0, stream,
                       x, w, csd, bias, cnt, wl, cap, out);
}

// Round 7
// 326.750 us; speedup vs baseline: 1.0361x; 1.0357x over previous
//
#include <hip/hip_runtime.h>
#include <hip/hip_bf16.h>
#include <math.h>

#define NB   16
#define CIN  128
#define COUT 128
#define HH   56
#define WW   56
#define LL   3136

typedef __attribute__((ext_vector_type(8))) short short8;
typedef __attribute__((ext_vector_type(16))) float f32x16;
typedef __attribute__((ext_vector_type(4))) float f32x4;
typedef __attribute__((ext_vector_type(4))) unsigned int uint4v;

// ---- mfma geometry ----
#define PXT    256            // pixels per block (linear)
#define NPXT   13             // ceil(3136/256)
#define XC     58             // cols incl halo
#define XPLANE 7424           // ushorts per x plane (8 rows * 58 * 16)
#define XUSH   14848          // ushorts x buffer (hi+lo) = 29,696 B
#define XUNITS 1856           // 16B units in x buffer
#define XHALF  928            // units per plane
#define WUSH   9216           // ushorts w buffer = 18,432 B (merged a/b, 16 oc)
#define WBYTES 18432          // bytes per (ocb,cg) weight image
#define WUNITS 1152           // 16B units in w buffer

// frag-major merged weight image: [tap 9][frag 2][lane 64][8 ush]
// frag 0 = Ah (rows 0-15 = a-fold hi, rows 16-31 = b-fold hi), frag 1 = Al (lo)

// xt layout: [cg 8][bat 16][plane 2][row 62][col 58][16ch] ushorts (halo zeroed)
#define XT_ROWS 62
#define XT_PLANE_USH (XT_ROWS*XC*16)   // 57536
#define XT_CG_STRIDE 3682304           // bytes per cg slab

// ---- workspace layout (bytes) ----
#define CSD_OFF 256
#define WSP_OFF 32768
#define XT_OFF  1212416
#define XT_SIZE 29458432
#define WL_OFF  (XT_OFF + XT_SIZE)     // needs ws_size >= ~31MB

// ---------------- merged prep: weights (+csd, +cnt zero) and x layout ----------------
__global__ void prep_kernel(const float* __restrict__ w, const float* __restrict__ bk,
                            const float* __restrict__ x,
                            double* __restrict__ csd, unsigned short* __restrict__ wsp,
                            unsigned short* __restrict__ xt, unsigned* __restrict__ cnt) {
    int bid = blockIdx.x;
    if (bid == 0 && threadIdx.x == 0) *cnt = 0u;
    if (bid < 576) {
        // ---- weight part: fold cos/sin (fp32), bf16 hi/lo split, merged frag-major image ----
        int i = bid * 256 + threadIdx.x;
        if (i >= 9*COUT*CIN) return;
        int k = i / (COUT*CIN);
        int rem = i - k*(COUT*CIN);
        int oc = rem >> 7, c = rem & 127;
        float bkv = bk[k*COUT + oc];
        if (c == 0) {                      // fp64 trig only for the fixup table
            double bd = (double)bkv;
            csd[k*COUT + oc]          = cos(bd);
            csd[9*COUT + k*COUT + oc] = sin(bd);
        }
        float ck = cosf(bkv), sk = sinf(bkv);
        float wv = w[i];
        float fa = ck * wv;
        float fb = sk * wv;
        __hip_bfloat16 ah = __float2bfloat16(fa);
        __hip_bfloat16 al = __float2bfloat16(fa - __bfloat162float(ah));
        __hip_bfloat16 bh = __float2bfloat16(fb);
        __hip_bfloat16 bl = __float2bfloat16(fb - __bfloat162float(bh));
        int ocb = oc >> 4;                    // 8 oc-blocks of 16
        int row_a = oc & 15;                  // A rows 0-15 = a-fold
        int cg = c >> 4, cp = c & 15;
        int lane_a = row_a + ((cp >> 3) << 5);
        int lane_b = 16 + row_a + ((cp >> 3) << 5);   // A rows 16-31 = b-fold
        int bp = cp & 7;
        size_t img = ((size_t)ocb*8 + cg) * WUSH;
        wsp[img + (size_t)((k*2+0)*64 + lane_a)*8 + bp] = *(unsigned short*)&ah;
        wsp[img + (size_t)((k*2+0)*64 + lane_b)*8 + bp] = *(unsigned short*)&bh;
        wsp[img + (size_t)((k*2+1)*64 + lane_a)*8 + bp] = *(unsigned short*)&al;
        wsp[img + (size_t)((k*2+1)*64 + lane_b)*8 + bp] = *(unsigned short*)&bl;
    } else {
        // ---- x part: bf16 hi/lo transposed padded layout ----
        int i = (bid - 576) * 256 + threadIdx.x;     // 852*256 = 218112
        if (i < 100352) {
            int c4 = i % 14; int t = i / 14;
            int row1 = t % 56; t /= 56;
            int bat = t & 15, cg = t >> 4;
            const float* xp = x + ((size_t)(bat*CIN + cg*16))*LL + row1*WW + c4*4;
            unsigned short hi[4][16], lo[4][16];
            #pragma unroll
            for (int j = 0; j < 16; j++) {
                f32x4 v = *(const f32x4*)(xp + (size_t)j*LL);
                #pragma unroll
                for (int cc = 0; cc < 4; cc++) {
                    float f = v[cc];
                    __hip_bfloat16 h = __float2bfloat16(f);
                    __hip_bfloat16 l = __float2bfloat16(f - __bfloat162float(h));
                    hi[cc][j] = *(unsigned short*)&h;
                    lo[cc][j] = *(unsigned short*)&l;
                }
            }
            size_t base = ((((size_t)cg*16 + bat)*2 + 0)*XT_ROWS + (row1+1))*XC + (c4*4 + 1);
            #pragma unroll
            for (int cc = 0; cc < 4; cc++) {
                unsigned short* dh = xt + (base + cc)*16;
                unsigned short* dl = dh + XT_PLANE_USH;
                *(uint4v*)dh       = *(const uint4v*)&hi[cc][0];
                *(uint4v*)(dh + 8) = *(const uint4v*)&hi[cc][8];
                *(uint4v*)dl       = *(const uint4v*)&lo[cc][0];
                *(uint4v*)(dl + 8) = *(const uint4v*)&lo[cc][8];
            }
        } else if (i < 218112) {
            int i2 = i - 100352;                      // < 117760
            int unit = i2 % 460; int t = i2 / 460;
            int pl = t & 1; t >>= 1;
            int bat = t & 15, cg = t >> 4;
            int row, c58;
            if (unit < 348) {
                int zr = unit / 58; c58 = unit - zr*58;
                row = (zr == 0) ? 0 : (56 + zr);
            } else {
                int u2 = unit - 348; row = 1 + (u2 >> 1); c58 = (u2 & 1) ? 57 : 0;
            }
            size_t base = ((((size_t)cg*16 + bat)*2 + pl)*XT_ROWS + row)*XC + c58;
            uint4v zz = {0u,0u,0u,0u};
            *(uint4v*)(xt + base*16)     = zz;
            *(uint4v*)(xt + base*16 + 8) = zz;
        }
    }
}

// ---------------- main MFMA kernel: 16-oc merged a/b, 48KB LDS, 3 blocks/CU ----------------
__global__ __launch_bounds__(256, 3)
void mfma_kernel(const unsigned short* __restrict__ xt, const unsigned short* __restrict__ wsp,
                 const float* __restrict__ bias, float* __restrict__ out,
                 unsigned* __restrict__ cnt, unsigned* __restrict__ wl, unsigned cap)
{
    __shared__ __align__(16) unsigned short SMX[XUSH];   // 29,696 B
    __shared__ __align__(16) unsigned short SMW[WUSH];   // 18,432 B  (total 48,128 -> 3 blk/CU)
    __shared__ float sm_bias[16];

    const int tid = threadIdx.x;
    // XCD-chunked bijective swizzle (1664 % 8 == 0); 8 ocb siblings stay on one XCD
    int bid = blockIdx.x;
    int wk = (bid & 7) * 208 + (bid >> 3);
    const int ocb = wk & 7; wk >>= 3;
    const int pxt = wk % NPXT;
    const int bat = wk / NPXT;
    const int l0  = pxt * PXT;
    const int o0  = ocb * 16;
    const int yf  = l0 / WW;

    const int lane = tid & 63;
    const int n    = lane & 31;
    const int kh   = lane >> 5;
    const int wave = tid >> 6;

    if (tid < 16) sm_bias[tid] = bias[o0 + tid];

    // per-lane global source offsets for x staging (bytes within one cg-slab)
    unsigned xoff[8];
    #pragma unroll
    for (int k = 0; k < 8; k++) {
        int u = tid + 256*k;
        int uc = u < XUNITS ? u : XUNITS-1;
        int pl = uc >= XHALF ? 1 : 0;
        int rem = uc - pl*XHALF;
        int q  = rem >> 1;
        int hl = rem & 1;
        int hg = hl ^ ((q >> 2) & 1);        // inverse of read-side bank swizzle
        int r  = q / XC;
        int c  = q - r*XC;
        xoff[k] = (unsigned)((((bat*2 + pl)*XT_ROWS + (yf + r))*XC + c)*32 + hg*16);
    }

    // B-frag pixel slots (2 groups of 32 px per wave)
    int q0g[2];
    #pragma unroll
    for (int g = 0; g < 2; g++) {
        int p  = l0 + wave*64 + g*32 + n;
        int pc = p < LL ? p : LL-1;
        int py = pc / WW, pxx = pc - py*WW;
        q0g[g] = (py - yf)*XC + pxx;
    }

    f32x16 acc[2];
    #pragma unroll
    for (int g = 0; g < 2; g++) {
        #pragma unroll
        for (int r = 0; r < 16; r++) acc[g][r] = 0.f;
    }

    const char* xtB  = (const char*)xt;
    const char* wspB = (const char*)wsp + (size_t)ocb * (8*(size_t)WBYTES);

    // async x stage: linear LDS dest, swizzle folded into per-lane source
    auto stage_x = [&](int chn) {
        const char* xp = xtB + (size_t)chn * XT_CG_STRIDE;
        #pragma unroll
        for (int k = 0; k < 7; k++) {
            __builtin_amdgcn_global_load_lds(
                (const __attribute__((address_space(1))) unsigned int*)(xp + xoff[k]),
                (__attribute__((address_space(3))) unsigned int*)&SMX[(wave*64 + 256*k)*8],
                16, 0, 0);
        }
        if (wave == 0)                             // 1856 = 7*256 + 64
            __builtin_amdgcn_global_load_lds(
                (const __attribute__((address_space(1))) unsigned int*)(xp + xoff[7]),
                (__attribute__((address_space(3))) unsigned int*)&SMX[1792*8],
                16, 0, 0);
    };
    // async w stage: frag-major image is a pure linear copy (1152 = 4*256 + 2*64 units)
    auto stage_w = [&](int chn) {
        const char* wp = wspB + (size_t)chn * (size_t)WBYTES;
        #pragma unroll
        for (int k = 0; k < 4; k++) {
            __builtin_amdgcn_global_load_lds(
                (const __attribute__((address_space(1))) unsigned int*)(wp + (tid + 256*k)*16),
                (__attribute__((address_space(3))) unsigned int*)&SMW[(wave*64 + 256*k)*8],
                16, 0, 0);
        }
        if (wave < 2)
            __builtin_amdgcn_global_load_lds(
                (const __attribute__((address_space(1))) unsigned int*)(wp + (1024 + tid)*16),
                (__attribute__((address_space(3))) unsigned int*)&SMW[(1024 + wave*64)*8],
                16, 0, 0);
    };

    // prologue: stage chunk 0, single drain
    stage_x(0);
    stage_w(0);
    __syncthreads();

    const unsigned short* awp = &SMW[lane*8];     // frag reads: awp + const offsets (conflict-free)

    #pragma unroll 1
    for (int ch = 0; ch < 8; ch++) {
        // tap loop: ZERO VMEM — pure ds_read + MFMA
        #pragma unroll
        for (int tap = 0; tap < 9; tap++) {
            const int ky = tap / 3, kx = tap - 3*ky;
            short8 Ah = *(const short8*)&awp[(tap*2+0)*512];
            short8 Al = *(const short8*)&awp[(tap*2+1)*512];
            __builtin_amdgcn_s_setprio(1);
            #pragma unroll
            for (int g = 0; g < 2; g++) {
                int q  = q0g[g] + ky*XC + kx;
                int si = q*16 + ((kh ^ ((q>>2)&1)) << 3);
                short8 Bh = *(const short8*)&SMX[si];
                short8 Bl = *(const short8*)&SMX[XPLANE + si];
                acc[g] = __builtin_amdgcn_mfma_f32_32x32x16_bf16(Al, Bh, acc[g], 0,0,0);
                acc[g] = __builtin_amdgcn_mfma_f32_32x32x16_bf16(Ah, Bl, acc[g], 0,0,0);
                acc[g] = __builtin_amdgcn_mfma_f32_32x32x16_bf16(Ah, Bh, acc[g], 0,0,0);
            }
            __builtin_amdgcn_s_setprio(0);
        }
        if (ch < 7) {
            __syncthreads();                // readers done with LDS
            stage_x(ch+1);                  // async refill
            stage_w(ch+1);
            __syncthreads();                // drain; 2 sibling blocks cover this
        }
    }

    // ---- epilogue: lane-local (a,b) pairs at acc regs (r, r+8) ----
    const float eps = 1e-05f;
    const float PIf = 3.14159265358979323846f;
    size_t obase = (size_t)bat * (2*COUT) * LL;

    #pragma unroll
    for (int g = 0; g < 2; g++) {
        const int pcol = wave*64 + g*32 + n;
        const int pp = l0 + pcol;
        #pragma unroll
        for (int r = 0; r < 8; r++) {
            int row16 = (r & 3) + 8*(r >> 2) + 4*kh;   // 0..15: local oc
            float av = acc[g][r];
            float bv = acc[g][r+8];
            bool flag = (pp < LL) &&
                        (fabsf(av) < 1.5e-4f || (bv < 1.05e-5f && bv > -2.05e-5f));
            unsigned long long m = __ballot(flag);
            if (m) {
                int leader = (int)__ffsll((long long)m) - 1;
                unsigned base = 0;
                if (lane == leader) base = atomicAdd(cnt, (unsigned)__popcll(m));
                base = __shfl(base, leader);
                if (flag) {
                    unsigned slot = base + (unsigned)__popcll(m & ((1ULL << lane) - 1ULL));
                    if (slot < cap)
                        wl[slot] = ((unsigned)(bat*LL + pp) << 7) | (unsigned)(o0 + row16);
                }
            }
            bool ag = av > 0.f, bg = bv > 0.f;
            bool eq = (ag == bg);
            float ratio = eq ? (bv / (av + eps)) : (av / (bv + eps));
            float at = atanf(ratio);
            float peak = eq ? (ag ? PIf*0.5f : -PIf*0.5f) : (bg ? 0.0f : -PIf);
            float th = peak - (eq ? at : -at);
            // o = sin(th)*a + cos(th)*b == sgn * rsqrt(1+r^2) * (eq ? a + r*b : r*a + b)
            float c = 1.0f / sqrtf(1.0f + ratio*ratio);
            float t = eq ? (av + ratio*bv) : (ratio*av + bv);
            bool pos = eq ? ag : bg;
            float o = (pos ? c : -c) * t;
            if (pp < LL) {
                out[obase + (size_t)(o0+row16)*LL + pp]      = o + sm_bias[row16];
                out[obase + (size_t)(COUT+o0+row16)*LL + pp] = th * (1.0f/PIf);
            }
        }
    }
}

// ---------------- fp64 fixup for near-discontinuity elements ----------------
__global__ __launch_bounds__(256)
void fixup_kernel(const float* __restrict__ x, const float* __restrict__ w,
                  const double* __restrict__ csd, const float* __restrict__ bias,
                  const unsigned* __restrict__ cnt, const unsigned* __restrict__ wl,
                  unsigned cap, float* __restrict__ out) {
    const int lane   = threadIdx.x & 63;
    const int waveid = (blockIdx.x * 256 + threadIdx.x) >> 6;
    const int nwaves = gridDim.x * 4;
    unsigned nf = *cnt; if (nf > cap) nf = cap;
    const double PI = 3.14159265358979323846;

    for (unsigned u = waveid; u < nf; u += nwaves) {
        unsigned idx = wl[u];
        int oc = idx & 127;
        unsigned rest = idx >> 7;
        int bb_ = rest / LL;
        int l   = rest - bb_*LL;
        int yy  = l / WW;
        int xx  = l - yy*WW;
        const float* xb = x + (size_t)bb_ * CIN * LL;

        double pa = 0.0, pb = 0.0;
        #pragma unroll
        for (int k = 0; k < 9; k++) {
            int dy = k/3, dx = k - dy*3;
            int py = yy + dy - 1, px = xx + dx - 1;
            double pk = 0.0;
            if ((unsigned)py < HH && (unsigned)px < WW) {
                int base = py*WW + px;
                const float* wr = w + k*(COUT*CIN) + oc*CIN;
                int c = lane;
                pk  = (double)xb[(size_t)c*LL + base] * (double)wr[c];
                c = lane + 64;
                pk += (double)xb[(size_t)c*LL + base] * (double)wr[c];
            }
            pa += csd[k*COUT + oc] * pk;
            pb += csd[9*COUT + k*COUT + oc] * pk;
        }
        #pragma unroll
        for (int off = 32; off > 0; off >>= 1) {
            pa += __shfl_xor(pa, off, 64);
            pb += __shfl_xor(pb, off, 64);
        }
        if (lane == 0) {
            bool ag = pa > 0.0, bg = pb > 0.0;
            bool eq = (ag == bg);
            double th;
            if (eq) th = (ag ? PI*0.5 : -PI*0.5) - atan(pb / (pa + 1e-5));
            else    th = (bg ? 0.0 : -PI) + atan(pa / (pb + 1e-5));
            double o = sin(th)*pa + cos(th)*pb + (double)bias[oc];
            out[((size_t)bb_*(2*COUT) + oc) * LL + l]        = (float)o;
            out[((size_t)bb_*(2*COUT) + COUT + oc) * LL + l] = (float)(th / PI);
        }
    }
}

extern "C" void kernel_launch(void* const* d_in, const int* in_sizes, int n_in,
                              void* d_out, int out_size, void* d_ws, size_t ws_size,
                              hipStream_t stream) {
    const float* x    = (const float*)d_in[0];
    const float* w    = (const float*)d_in[1];
    const float* bk   = (const float*)d_in[2];
    const float* bias = (const float*)d_in[3];
    float* out = (float*)d_out;

    char* ws = (char*)d_ws;
    unsigned*       cnt = (unsigned*)ws;
    double*         csd = (double*)(ws + CSD_OFF);
    unsigned short* wsp = (unsigned short*)(ws + WSP_OFF);
    unsigned short* xt  = (unsigned short*)(ws + XT_OFF);
    unsigned*       wl  = (unsigned*)(ws + WL_OFF);
    unsigned cap = (ws_size > (size_t)WL_OFF + 4096) ? (unsigned)((ws_size - WL_OFF) / 4) : 0u;

    hipLaunchKernelGGL(prep_kernel,  dim3(1428), dim3(256), 0, stream,
                       w, bk, x, csd, wsp, xt, cnt);
    hipLaunchKernelGGL(mfma_kernel,  dim3(NB*NPXT*8), dim3(256), 0, stream,
                       xt, wsp, bias, out, cnt, wl, cap);
    hipLaunchKernelGGL(fixup_kernel, dim3(256), dim3(256), 0, stream,
                       x, w, csd, bias, cnt, wl, cap, out);
}